// Round 6
// baseline (224.091 us; speedup 1.0000x reference)
//
#include <hip/hip_runtime.h>

// B=4, H=8, M=2048, K=2048, N=64, NNZ = 4,194,304
// out[seg, :] = sum over nnz with seg=bh*M+m of values[i] * b[bh, idx_k[i], :]
constexpr int N_COLS = 64;
constexpr int K_DIM  = 2048;
constexpr int M_DIM  = 2048;
constexpr int SEGS   = 32 * 2048;          // 65536 output rows
constexpr int NBUCK  = 512;                // coarse buckets: seg >> 7
constexpr int SEG_PER_BUCK = SEGS / NBUCK; // 128 rows per bucket
constexpr int PART_T = 512;
constexpr int PART_E = 16;
constexpr int TILE   = PART_T * PART_E;    // 8192 entries per block
constexpr int CAP2   = 8192;               // bucket region = exact mean; excess -> ovf
constexpr int CSTR   = 16;                 // cursor stride: one counter per 64B line
constexpr int OVL_CAP = 640;               // per-bucket LDS overflow cap (~2x max excess)
constexpr size_t OVFCNT_OFF = 32768;       // global overflow cursor (in ws header)
constexpr size_t OVFBUF_OFF = 40960;       // global overflow buffer (in ws header)
constexpr int OVF_GCAP = (int)((524288 - OVFBUF_OFF) / 8);  // 60416 entries (~3x expected)

// Pair layout in memory: v FIRST, k SECOND.  int2 over a Pair = {vbits, k}.
// Pair.k packing: bits 8..18 = idx_k<<8 (byte offset into the 512KB bh slab),
// bits 19..25 = segLocal.  Overflow entries additionally pack bucket id into
// free bits: bits 0..7 = bkt[7:0], bit 26 = bkt[8].
// LESSONS: (r3) wave-uniform GLOBAL loads scalarize into an s_load latency
// chain; (r3/r4) LDS float atomicAdd lowers to a CAS loop (22x collapse) —
// int LDS atomics only, accumulate in registers, uniform reads via LDS.
struct Pair { float v; int k; };

// ---------- fallback: wave-per-nnz atomic scatter ----------
__global__ void spmm_coo_atomic(const float* __restrict__ values,
                                const float* __restrict__ b,
                                const int*   __restrict__ idx_bh,
                                const int*   __restrict__ idx_m,
                                const int*   __restrict__ idx_k,
                                float*       __restrict__ out,
                                int nnz) {
    long long gid = (long long)blockIdx.x * blockDim.x + threadIdx.x;
    int nz   = (int)(gid >> 6);
    int lane = (int)(gid & 63);
    if (nz >= nnz) return;
    float bval = b[((size_t)idx_bh[nz] * K_DIM + idx_k[nz]) * N_COLS + lane];
    atomicAdd(&out[((size_t)idx_bh[nz] * M_DIM + idx_m[nz]) * N_COLS + lane],
              values[nz] * bval);
}

// ---------- phase 1: block-aggregated multi-split into 512 fixed regions ----------
// Per-thread CONTIGUOUS 16 entries => float4/int4 vector loads.
// Relative cursors; entry global rank g = resv + localRank.  g < CAP2 lands in
// the bucket's fixed region (the region is an exact dense prefix: every slot in
// [0,CAP2) is claimed by exactly one entry); g >= CAP2 appends to the global
// overflow list with the bucket id packed into pk's free bits.
__global__ __launch_bounds__(PART_T)
void partition512(const float* __restrict__ values,
                  const int*   __restrict__ idx_bh,
                  const int*   __restrict__ idx_m,
                  const int*   __restrict__ idx_k,
                  int*  __restrict__ cursor,
                  int*  __restrict__ ovfcnt,
                  Pair* __restrict__ ovf,
                  Pair* __restrict__ packed, int nnz) {
    __shared__ int lcount[NBUCK];
    __shared__ int sbase[NBUCK];
    int t = threadIdx.x;
    lcount[t] = 0;
    __syncthreads();

    int e0 = blockIdx.x * TILE + t * PART_E;   // 16 contiguous entries per thread
    float v[PART_E];
    int   pk[PART_E];
    short bkt[PART_E];
    short rnk[PART_E];

    if (e0 + PART_E <= nnz) {
        const float4* vv4 = (const float4*)(values + e0);
        const int4*   bh4 = (const int4*)(idx_bh + e0);
        const int4*   mm4 = (const int4*)(idx_m + e0);
        const int4*   kk4 = (const int4*)(idx_k + e0);
        #pragma unroll
        for (int q = 0; q < PART_E / 4; ++q) {
            float4 vq = vv4[q];
            int4   bq = bh4[q], mq = mm4[q], kq = kk4[q];
            int s0 = bq.x * M_DIM + mq.x;
            int s1 = bq.y * M_DIM + mq.y;
            int s2 = bq.z * M_DIM + mq.z;
            int s3 = bq.w * M_DIM + mq.w;
            v[4*q+0]=vq.x; pk[4*q+0]=(kq.x<<8)|((s0&127)<<19); bkt[4*q+0]=(short)(s0>>7);
            rnk[4*q+0]=(short)atomicAdd(&lcount[s0>>7],1);
            v[4*q+1]=vq.y; pk[4*q+1]=(kq.y<<8)|((s1&127)<<19); bkt[4*q+1]=(short)(s1>>7);
            rnk[4*q+1]=(short)atomicAdd(&lcount[s1>>7],1);
            v[4*q+2]=vq.z; pk[4*q+2]=(kq.z<<8)|((s2&127)<<19); bkt[4*q+2]=(short)(s2>>7);
            rnk[4*q+2]=(short)atomicAdd(&lcount[s2>>7],1);
            v[4*q+3]=vq.w; pk[4*q+3]=(kq.w<<8)|((s3&127)<<19); bkt[4*q+3]=(short)(s3>>7);
            rnk[4*q+3]=(short)atomicAdd(&lcount[s3>>7],1);
        }
    } else {
        #pragma unroll
        for (int i = 0; i < PART_E; ++i) {
            int e = e0 + i;
            if (e < nnz) {
                int seg = idx_bh[e] * M_DIM + idx_m[e];
                int bu  = seg >> 7;
                v[i]  = values[e];
                pk[i] = (idx_k[e] << 8) | ((seg & 127) << 19);
                bkt[i] = (short)bu;
                rnk[i] = (short)atomicAdd(&lcount[bu], 1);
            } else bkt[i] = -1;
        }
    }
    __syncthreads();
    int c = lcount[t];
    // one padded-line global atomic per (block, non-empty bucket)
    sbase[t] = (c > 0) ? atomicAdd(&cursor[t * CSTR], c) : 0;
    __syncthreads();
    #pragma unroll
    for (int i = 0; i < PART_E; ++i) {
        if (bkt[i] >= 0) {
            int g = sbase[bkt[i]] + rnk[i];
            Pair p; p.v = v[i];
            if (g < CAP2) {
                p.k = pk[i];
                packed[(size_t)bkt[i] * CAP2 + g] = p;
            } else {
                int o = atomicAdd(ovfcnt, 1);
                if (o < OVF_GCAP) {
                    p.k = pk[i] | ((int)bkt[i] & 0xFF) | ((((int)bkt[i]) >> 8) << 26);
                    ovf[o] = p;
                }
            }
        }
    }
}

// ---------- phase 2 (proven 61.5 us structure): sort in LDS, ----------
// ---------- uniform ds_read walk, readfirstlane gather, REGISTER acc ----------
// LDS: ps 70.7KB + ovl 5KB + h/cur 1KB = ~76.9KB => 2 blocks/CU, 32 waves/CU.
// All LDS atomics are INT (native).  packed read from global ONCE into
// registers; overflow list (~18K entries chip-wide) scanned coalesced, matches
// (~36/bucket) appended to an LDS side list and merged through the same
// hist/scan/scatter.
__global__ __launch_bounds__(1024)
void sort_accum(const Pair* __restrict__ packed,
                const int*  __restrict__ cursor,   // relative counts (stride CSTR)
                const int*  __restrict__ ovfcnt,
                const Pair* __restrict__ ovf,
                const float* __restrict__ b,
                float* __restrict__ out) {
    __shared__ int2 ps[CAP2 + OVL_CAP + 8];   // {byteoff (k<<8), vbits}, seg-sorted
    __shared__ int2 ovl[OVL_CAP];
    __shared__ int h[SEG_PER_BUCK];
    __shared__ int cur[SEG_PER_BUCK];
    __shared__ int ovl_n;

    int t = threadIdx.x;
    // XCD swizzle: xcd = blk&7 owns bh in [xcd*4, xcd*4+4) => 2MB of b per XCD L2
    int i   = blockIdx.x;
    int bkt = (i & 7) * 64 + (i >> 3);
    int cnt = cursor[bkt * CSTR];
    int L = cnt;
    if (L < 0)    L = 0;
    if (L > CAP2) L = CAP2;   // excess lives in the overflow list

    if (t < SEG_PER_BUCK) h[t] = 0;
    if (t == 0) ovl_n = 0;
    __syncthreads();

    // stage region entries in registers, histogram from registers (int atomics)
    const int2* src = (const int2*)(packed + (size_t)bkt * CAP2);   // {vbits, k}
    int2 reg[8];                                                    // 8*1024 = CAP2
    #pragma unroll
    for (int q = 0; q < 8; ++q) {
        int idx = t + q * 1024;
        if (idx < L) {
            reg[q] = src[idx];
            atomicAdd(&h[(reg[q].y >> 19) & 127], 1);
        }
    }
    // overflow scan: coalesced per-lane loads (NOT uniform — no scalarization)
    int ovfN = ovfcnt[0];
    if (ovfN > OVF_GCAP) ovfN = OVF_GCAP;
    const int2* osrc = (const int2*)ovf;
    for (int o = t; o < ovfN; o += 1024) {
        int2 e = osrc[o];
        int eb = (e.y & 0xFF) | ((e.y >> 18) & 0x100);
        if (eb == bkt) {
            int pos = atomicAdd(&ovl_n, 1);
            if (pos < OVL_CAP) {
                ovl[pos] = e;
                atomicAdd(&h[(e.y >> 19) & 127], 1);
            }
        }
    }
    __syncthreads();

    // inclusive Hillis-Steele scan of h[0..127]
    for (int d = 1; d < SEG_PER_BUCK; d <<= 1) {
        int x = 0;
        if (t < SEG_PER_BUCK && t >= d) x = h[t - d];
        __syncthreads();
        if (t < SEG_PER_BUCK && t >= d) h[t] += x;
        __syncthreads();
    }
    if (t < SEG_PER_BUCK) cur[t] = (t == 0) ? 0 : h[t - 1];
    __syncthreads();

    // scatter region entries from registers into segment-sorted LDS
    #pragma unroll
    for (int q = 0; q < 8; ++q) {
        int idx = t + q * 1024;
        if (idx < L) {
            int pos = atomicAdd(&cur[(reg[q].y >> 19) & 127], 1);
            ps[pos] = make_int2(reg[q].y & 0x0007FF00, reg[q].x);
        }
    }
    // scatter overflow entries (bucket bits don't alias k/seg fields)
    int on = ovl_n; if (on > OVL_CAP) on = OVL_CAP;
    if (t < on) {
        int2 e = ovl[t];
        int pos = atomicAdd(&cur[(e.y >> 19) & 127], 1);
        ps[pos] = make_int2(e.y & 0x0007FF00, e.x);
    }
    __syncthreads();
    if (t < 8) ps[h[SEG_PER_BUCK - 1] + t] = make_int2(0, 0);  // tail zero pad
    __syncthreads();

    // accumulate: 16 waves, wave w handles segs [w*8, w*8+8).  Uniform ds_read
    // (hardware broadcast, not scalarizable), readfirstlane -> saddr gather,
    // REGISTER accumulators.
    int lane = t & 63;
    int w    = t >> 6;
    int bh   = bkt >> 4;
    const char* bbyte = (const char*)(b + ((size_t)bh << 17));  // bh * K_DIM * N_COLS
    size_t obase = ((size_t)bkt << 13);                         // bkt * 128 * 64

    for (int s = w * 8; s < w * 8 + 8; ++s) {
        int js = (s == 0) ? 0 : h[s - 1];
        int je = h[s];
        float a0 = 0.f, a1 = 0.f, a2 = 0.f, a3 = 0.f;
        int j = js;
        // main: 8 entries/iter, uniform broadcast reads, 8 gathers in flight
        for (; j + 8 <= je; j += 8) {
            int2 e0 = ps[j+0], e1 = ps[j+1], e2 = ps[j+2], e3 = ps[j+3];
            int2 e4 = ps[j+4], e5 = ps[j+5], e6 = ps[j+6], e7 = ps[j+7];
            const float* r0 = (const float*)(bbyte + __builtin_amdgcn_readfirstlane(e0.x));
            const float* r1 = (const float*)(bbyte + __builtin_amdgcn_readfirstlane(e1.x));
            const float* r2 = (const float*)(bbyte + __builtin_amdgcn_readfirstlane(e2.x));
            const float* r3 = (const float*)(bbyte + __builtin_amdgcn_readfirstlane(e3.x));
            const float* r4 = (const float*)(bbyte + __builtin_amdgcn_readfirstlane(e4.x));
            const float* r5 = (const float*)(bbyte + __builtin_amdgcn_readfirstlane(e5.x));
            const float* r6 = (const float*)(bbyte + __builtin_amdgcn_readfirstlane(e6.x));
            const float* r7 = (const float*)(bbyte + __builtin_amdgcn_readfirstlane(e7.x));
            float b0 = r0[lane], b1 = r1[lane], b2 = r2[lane], b3 = r3[lane];
            float b4 = r4[lane], b5 = r5[lane], b6 = r6[lane], b7 = r7[lane];
            a0 += __int_as_float(e0.y) * b0; a1 += __int_as_float(e1.y) * b1;
            a2 += __int_as_float(e2.y) * b2; a3 += __int_as_float(e3.y) * b3;
            a0 += __int_as_float(e4.y) * b4; a1 += __int_as_float(e5.y) * b5;
            a2 += __int_as_float(e6.y) * b6; a3 += __int_as_float(e7.y) * b7;
        }
        // tail: ONE masked 8-wide iteration (over-read hits next segment's valid
        // offsets or the zero pad — values masked to 0)
        if (j < je) {
            int2 e0 = ps[j+0], e1 = ps[j+1], e2 = ps[j+2], e3 = ps[j+3];
            int2 e4 = ps[j+4], e5 = ps[j+5], e6 = ps[j+6], e7 = ps[j+7];
            const float* r0 = (const float*)(bbyte + __builtin_amdgcn_readfirstlane(e0.x));
            const float* r1 = (const float*)(bbyte + __builtin_amdgcn_readfirstlane(e1.x));
            const float* r2 = (const float*)(bbyte + __builtin_amdgcn_readfirstlane(e2.x));
            const float* r3 = (const float*)(bbyte + __builtin_amdgcn_readfirstlane(e3.x));
            const float* r4 = (const float*)(bbyte + __builtin_amdgcn_readfirstlane(e4.x));
            const float* r5 = (const float*)(bbyte + __builtin_amdgcn_readfirstlane(e5.x));
            const float* r6 = (const float*)(bbyte + __builtin_amdgcn_readfirstlane(e6.x));
            const float* r7 = (const float*)(bbyte + __builtin_amdgcn_readfirstlane(e7.x));
            float b0 = r0[lane], b1 = r1[lane], b2 = r2[lane], b3 = r3[lane];
            float b4 = r4[lane], b5 = r5[lane], b6 = r6[lane], b7 = r7[lane];
            float v0 = (j+0 < je) ? __int_as_float(e0.y) : 0.f;
            float v1 = (j+1 < je) ? __int_as_float(e1.y) : 0.f;
            float v2 = (j+2 < je) ? __int_as_float(e2.y) : 0.f;
            float v3 = (j+3 < je) ? __int_as_float(e3.y) : 0.f;
            float v4 = (j+4 < je) ? __int_as_float(e4.y) : 0.f;
            float v5 = (j+5 < je) ? __int_as_float(e5.y) : 0.f;
            float v6 = (j+6 < je) ? __int_as_float(e6.y) : 0.f;
            float v7 = (j+7 < je) ? __int_as_float(e7.y) : 0.f;
            a0 += v0 * b0; a1 += v1 * b1; a2 += v2 * b2; a3 += v3 * b3;
            a0 += v4 * b4; a1 += v5 * b5; a2 += v6 * b6; a3 += v7 * b7;
        }
        out[obase + ((size_t)s << 6) + lane] = (a0 + a1) + (a2 + a3);
    }
}

extern "C" void kernel_launch(void* const* d_in, const int* in_sizes, int n_in,
                              void* d_out, int out_size, void* d_ws, size_t ws_size,
                              hipStream_t stream) {
    const float* values = (const float*)d_in[0];
    const float* b      = (const float*)d_in[1];
    const int*   idx_bh = (const int*)d_in[2];
    const int*   idx_m  = (const int*)d_in[3];
    const int*   idx_k  = (const int*)d_in[4];
    float*       out    = (float*)d_out;
    const int    nnz    = in_sizes[0];

    // ws layout (bytes):
    //   [cursor: 512*CSTR ints @0 (32KB)][ovfcnt @32KB][ovf buf @40KB..512KB]
    //   [packed @512KB: 512 regions x 8192 entries x 8B = 32MB]
    // Memory need == old dense-path need (512KB + nnz*8) — the fixed-cap path
    // now runs wherever dense ran, deleting hist512 + scan512 + 2 launch gaps.
    const size_t packed_off = 512 * 1024;
    const size_t need = packed_off + (size_t)NBUCK * CAP2 * sizeof(Pair);

    int*  cursor = (int*)d_ws;                             // padded: one int per 64B
    int*  ovfcnt = (int*)((char*)d_ws + OVFCNT_OFF);
    Pair* ovfbuf = (Pair*)((char*)d_ws + OVFBUF_OFF);
    Pair* packed = (Pair*)((char*)d_ws + packed_off);

    const int nblk = (nnz + TILE - 1) / TILE;   // 512

    if (ws_size >= need) {
        hipMemsetAsync(d_ws, 0, OVFBUF_OFF, stream);       // cursors + ovf cursor
        partition512<<<nblk, PART_T, 0, stream>>>(values, idx_bh, idx_m, idx_k,
                                                  cursor, ovfcnt, ovfbuf, packed, nnz);
        sort_accum<<<NBUCK, 1024, 0, stream>>>(packed, cursor, ovfcnt, ovfbuf, b, out);
    } else {
        hipMemsetAsync(d_out, 0, (size_t)out_size * sizeof(float), stream);
        long long total = (long long)nnz * N_COLS;
        spmm_coo_atomic<<<(unsigned)((total + 255) / 256), 256, 0, stream>>>(
            values, b, idx_bh, idx_m, idx_k, out, nnz);
    }
}

// Round 7
// 194.112 us; speedup vs baseline: 1.1544x; 1.1544x over previous
//
#include <hip/hip_runtime.h>

// B=4, H=8, M=2048, K=2048, N=64, NNZ = 4,194,304
// out[seg, :] = sum over nnz with seg=bh*M+m of values[i] * b[bh, idx_k[i], :]
constexpr int N_COLS = 64;
constexpr int K_DIM  = 2048;
constexpr int M_DIM  = 2048;
constexpr int SEGS   = 32 * 2048;          // 65536 output rows
constexpr int NBUCK  = 512;                // coarse buckets: seg >> 7
constexpr int SEG_PER_BUCK = SEGS / NBUCK; // 128 rows per bucket
constexpr int PART_T = 512;
constexpr int PART_E = 16;
constexpr int TILE   = PART_T * PART_E;    // 8192 entries per block
constexpr int CAP2   = 8192;               // bucket region = exact mean; excess -> ovf
constexpr int CSTR   = 16;                 // cursor stride: one counter per 64B line
constexpr int OVL_CAP = 640;               // per-bucket LDS overflow cap (~2x max excess)
constexpr size_t OVFCNT_OFF = 32768;       // global overflow cursor (in ws header)
constexpr size_t OVFBUF_OFF = 40960;       // global overflow buffer (in ws header)
constexpr int OVF_GCAP = (int)((524288 - OVFBUF_OFF) / 8);  // 60416 entries (~3x expected)

// Pair layout in memory: v FIRST, k SECOND.  int2 over a Pair = {vbits, k}.
// Pair.k packing: bits 8..18 = idx_k<<8 (byte offset into the 512KB bh slab),
// bits 19..25 = segLocal, bits 0..7 = bkt[7:0], bit 26 = bkt[8].
// The bucket bits are disjoint from the k/seg fields, and sort_accum's decode
// masks (0x0007FF00 and (>>19)&127) ignore them — so ALL entries carry their
// bucket id everywhere (region + overflow share one format).
// LESSONS: (r3) wave-uniform GLOBAL loads scalarize into an s_load latency
// chain; (r3/r4) LDS float atomicAdd lowers to a CAS loop (22x collapse) —
// int LDS atomics only, accumulate in registers, uniform reads via LDS;
// (r6) per-entry scattered 8B global stores -> 3x HBM write amplification,
// latency-bound at 2.6% VALUBusy — write-combine through LDS.
struct Pair { float v; int k; };

// ---------- fallback: wave-per-nnz atomic scatter ----------
__global__ void spmm_coo_atomic(const float* __restrict__ values,
                                const float* __restrict__ b,
                                const int*   __restrict__ idx_bh,
                                const int*   __restrict__ idx_m,
                                const int*   __restrict__ idx_k,
                                float*       __restrict__ out,
                                int nnz) {
    long long gid = (long long)blockIdx.x * blockDim.x + threadIdx.x;
    int nz   = (int)(gid >> 6);
    int lane = (int)(gid & 63);
    if (nz >= nnz) return;
    float bval = b[((size_t)idx_bh[nz] * K_DIM + idx_k[nz]) * N_COLS + lane];
    atomicAdd(&out[((size_t)idx_bh[nz] * M_DIM + idx_m[nz]) * N_COLS + lane],
              values[nz] * bval);
}

// ---------- phase 1: multi-split with LDS write-combining ----------
// 1) per-thread 16 contiguous entries, vector loads, ranks via LDS int atomics
// 2) one global cursor atomic per (block, bucket) reserves [sbase, sbase+c)
// 3) block-local 512-scan -> bucket-sorted LDS buffer (ebuf)
// 4) COALESCED flush: thread p writes ebuf[p] to packed[bkt*CAP2 + gadj[bkt]+p]
//    — consecutive p share buckets => contiguous ~128B runs, full-line stores.
//    gpos >= CAP2 entries append to the global overflow list instead.
__global__ __launch_bounds__(PART_T)
void partition512(const float* __restrict__ values,
                  const int*   __restrict__ idx_bh,
                  const int*   __restrict__ idx_m,
                  const int*   __restrict__ idx_k,
                  int*  __restrict__ cursor,
                  int*  __restrict__ ovfcnt,
                  Pair* __restrict__ ovf,
                  Pair* __restrict__ packed, int nnz) {
    __shared__ int2 ebuf[TILE];        // 64 KB: bucket-sorted entries
    __shared__ int lcount[NBUCK];      // per-bucket count -> ranks
    __shared__ int sc[NBUCK];          // scan temp, then gadj = sbase - lstart
    __shared__ int lstart[NBUCK];      // exclusive prefix (local bucket start)
    __shared__ int total_s;

    int t = threadIdx.x;
    lcount[t] = 0;
    __syncthreads();

    int e0 = blockIdx.x * TILE + t * PART_E;   // 16 contiguous entries per thread
    float v[PART_E];
    int   pk[PART_E];
    short bkt[PART_E];
    short rnk[PART_E];

    if (e0 + PART_E <= nnz) {
        const float4* vv4 = (const float4*)(values + e0);
        const int4*   bh4 = (const int4*)(idx_bh + e0);
        const int4*   mm4 = (const int4*)(idx_m + e0);
        const int4*   kk4 = (const int4*)(idx_k + e0);
        #pragma unroll
        for (int q = 0; q < PART_E / 4; ++q) {
            float4 vq = vv4[q];
            int4   bq = bh4[q], mq = mm4[q], kq = kk4[q];
            int s0 = bq.x * M_DIM + mq.x;
            int s1 = bq.y * M_DIM + mq.y;
            int s2 = bq.z * M_DIM + mq.z;
            int s3 = bq.w * M_DIM + mq.w;
            int b0 = s0 >> 7, b1 = s1 >> 7, b2 = s2 >> 7, b3 = s3 >> 7;
            v[4*q+0]=vq.x; pk[4*q+0]=(kq.x<<8)|((s0&127)<<19)|(b0&0xFF)|((b0>>8)<<26);
            bkt[4*q+0]=(short)b0; rnk[4*q+0]=(short)atomicAdd(&lcount[b0],1);
            v[4*q+1]=vq.y; pk[4*q+1]=(kq.y<<8)|((s1&127)<<19)|(b1&0xFF)|((b1>>8)<<26);
            bkt[4*q+1]=(short)b1; rnk[4*q+1]=(short)atomicAdd(&lcount[b1],1);
            v[4*q+2]=vq.z; pk[4*q+2]=(kq.z<<8)|((s2&127)<<19)|(b2&0xFF)|((b2>>8)<<26);
            bkt[4*q+2]=(short)b2; rnk[4*q+2]=(short)atomicAdd(&lcount[b2],1);
            v[4*q+3]=vq.w; pk[4*q+3]=(kq.w<<8)|((s3&127)<<19)|(b3&0xFF)|((b3>>8)<<26);
            bkt[4*q+3]=(short)b3; rnk[4*q+3]=(short)atomicAdd(&lcount[b3],1);
        }
    } else {
        #pragma unroll
        for (int i = 0; i < PART_E; ++i) {
            int e = e0 + i;
            if (e < nnz) {
                int seg = idx_bh[e] * M_DIM + idx_m[e];
                int bu  = seg >> 7;
                v[i]  = values[e];
                pk[i] = (idx_k[e] << 8) | ((seg & 127) << 19)
                      | (bu & 0xFF) | ((bu >> 8) << 26);
                bkt[i] = (short)bu;
                rnk[i] = (short)atomicAdd(&lcount[bu], 1);
            } else bkt[i] = -1;
        }
    }
    __syncthreads();

    int c = lcount[t];
    // one padded-line global atomic per (block, non-empty bucket)
    int sbase = (c > 0) ? atomicAdd(&cursor[t * CSTR], c) : 0;

    // inclusive Hillis-Steele scan of lcount (512 threads, 9 steps)
    sc[t] = c;
    __syncthreads();
    for (int d = 1; d < NBUCK; d <<= 1) {
        int x = (t >= d) ? sc[t - d] : 0;
        __syncthreads();
        sc[t] += x;
        __syncthreads();
    }
    int ls = sc[t] - c;          // exclusive prefix
    lstart[t] = ls;
    if (t == NBUCK - 1) total_s = sc[t];
    __syncthreads();
    sc[t] = sbase - ls;          // gadj: gpos = gadj[bkt] + local_pos

    // scatter into bucket-sorted LDS buffer
    #pragma unroll
    for (int i = 0; i < PART_E; ++i) {
        if (bkt[i] >= 0)
            ebuf[lstart[bkt[i]] + rnk[i]] = make_int2(__float_as_int(v[i]), pk[i]);
    }
    __syncthreads();   // ebuf + gadj ready

    // coalesced flush: contiguous runs per bucket
    int total = total_s;
    for (int p = t; p < total; p += PART_T) {
        int2 e = ebuf[p];
        int bu = (e.y & 0xFF) | ((e.y >> 18) & 0x100);
        int gpos = sc[bu] + p;
        if (gpos < CAP2) {
            *(int2*)&packed[(size_t)bu * CAP2 + gpos] = e;
        } else {
            int o = atomicAdd(ovfcnt, 1);
            if (o < OVF_GCAP) *(int2*)&ovf[o] = e;
        }
    }
}

// ---------- phase 2 (proven structure): sort in LDS, uniform ds_read walk, ----------
// ---------- readfirstlane gather, REGISTER accumulate ----------
// LDS ~76.9KB => 2 blocks/CU, 32 waves/CU.  All LDS atomics INT (native).
// packed read ONCE into registers; overflow list (~18K entries chip-wide)
// scanned coalesced, matches merged through the same hist/scan/scatter.
__global__ __launch_bounds__(1024)
void sort_accum(const Pair* __restrict__ packed,
                const int*  __restrict__ cursor,   // relative counts (stride CSTR)
                const int*  __restrict__ ovfcnt,
                const Pair* __restrict__ ovf,
                const float* __restrict__ b,
                float* __restrict__ out) {
    __shared__ int2 ps[CAP2 + OVL_CAP + 8];   // {byteoff (k<<8), vbits}, seg-sorted
    __shared__ int2 ovl[OVL_CAP];
    __shared__ int h[SEG_PER_BUCK];
    __shared__ int cur[SEG_PER_BUCK];
    __shared__ int ovl_n;

    int t = threadIdx.x;
    // XCD swizzle: xcd = blk&7 owns bh in [xcd*4, xcd*4+4) => 2MB of b per XCD L2
    int i   = blockIdx.x;
    int bkt = (i & 7) * 64 + (i >> 3);
    int cnt = cursor[bkt * CSTR];
    int L = cnt;
    if (L < 0)    L = 0;
    if (L > CAP2) L = CAP2;   // excess lives in the overflow list

    if (t < SEG_PER_BUCK) h[t] = 0;
    if (t == 0) ovl_n = 0;
    __syncthreads();

    // stage region entries in registers, histogram from registers (int atomics)
    const int2* src = (const int2*)(packed + (size_t)bkt * CAP2);   // {vbits, k}
    int2 reg[8];                                                    // 8*1024 = CAP2
    #pragma unroll
    for (int q = 0; q < 8; ++q) {
        int idx = t + q * 1024;
        if (idx < L) {
            reg[q] = src[idx];
            atomicAdd(&h[(reg[q].y >> 19) & 127], 1);
        }
    }
    // overflow scan: coalesced per-lane loads (NOT uniform — no scalarization)
    int ovfN = ovfcnt[0];
    if (ovfN > OVF_GCAP) ovfN = OVF_GCAP;
    const int2* osrc = (const int2*)ovf;
    for (int o = t; o < ovfN; o += 1024) {
        int2 e = osrc[o];
        int eb = (e.y & 0xFF) | ((e.y >> 18) & 0x100);
        if (eb == bkt) {
            int pos = atomicAdd(&ovl_n, 1);
            if (pos < OVL_CAP) {
                ovl[pos] = e;
                atomicAdd(&h[(e.y >> 19) & 127], 1);
            }
        }
    }
    __syncthreads();

    // inclusive Hillis-Steele scan of h[0..127]
    for (int d = 1; d < SEG_PER_BUCK; d <<= 1) {
        int x = 0;
        if (t < SEG_PER_BUCK && t >= d) x = h[t - d];
        __syncthreads();
        if (t < SEG_PER_BUCK && t >= d) h[t] += x;
        __syncthreads();
    }
    if (t < SEG_PER_BUCK) cur[t] = (t == 0) ? 0 : h[t - 1];
    __syncthreads();

    // scatter region entries from registers into segment-sorted LDS
    #pragma unroll
    for (int q = 0; q < 8; ++q) {
        int idx = t + q * 1024;
        if (idx < L) {
            int pos = atomicAdd(&cur[(reg[q].y >> 19) & 127], 1);
            ps[pos] = make_int2(reg[q].y & 0x0007FF00, reg[q].x);
        }
    }
    // scatter overflow entries (bucket bits don't alias k/seg fields)
    int on = ovl_n; if (on > OVL_CAP) on = OVL_CAP;
    if (t < on) {
        int2 e = ovl[t];
        int pos = atomicAdd(&cur[(e.y >> 19) & 127], 1);
        ps[pos] = make_int2(e.y & 0x0007FF00, e.x);
    }
    __syncthreads();
    if (t < 8) ps[h[SEG_PER_BUCK - 1] + t] = make_int2(0, 0);  // tail zero pad
    __syncthreads();

    // accumulate: 16 waves, wave w handles segs [w*8, w*8+8).  Uniform ds_read
    // (hardware broadcast, not scalarizable), readfirstlane -> saddr gather,
    // REGISTER accumulators.
    int lane = t & 63;
    int w    = t >> 6;
    int bh   = bkt >> 4;
    const char* bbyte = (const char*)(b + ((size_t)bh << 17));  // bh * K_DIM * N_COLS
    size_t obase = ((size_t)bkt << 13);                         // bkt * 128 * 64

    for (int s = w * 8; s < w * 8 + 8; ++s) {
        int js = (s == 0) ? 0 : h[s - 1];
        int je = h[s];
        float a0 = 0.f, a1 = 0.f, a2 = 0.f, a3 = 0.f;
        int j = js;
        // main: 8 entries/iter, uniform broadcast reads, 8 gathers in flight
        for (; j + 8 <= je; j += 8) {
            int2 e0 = ps[j+0], e1 = ps[j+1], e2 = ps[j+2], e3 = ps[j+3];
            int2 e4 = ps[j+4], e5 = ps[j+5], e6 = ps[j+6], e7 = ps[j+7];
            const float* r0 = (const float*)(bbyte + __builtin_amdgcn_readfirstlane(e0.x));
            const float* r1 = (const float*)(bbyte + __builtin_amdgcn_readfirstlane(e1.x));
            const float* r2 = (const float*)(bbyte + __builtin_amdgcn_readfirstlane(e2.x));
            const float* r3 = (const float*)(bbyte + __builtin_amdgcn_readfirstlane(e3.x));
            const float* r4 = (const float*)(bbyte + __builtin_amdgcn_readfirstlane(e4.x));
            const float* r5 = (const float*)(bbyte + __builtin_amdgcn_readfirstlane(e5.x));
            const float* r6 = (const float*)(bbyte + __builtin_amdgcn_readfirstlane(e6.x));
            const float* r7 = (const float*)(bbyte + __builtin_amdgcn_readfirstlane(e7.x));
            float b0 = r0[lane], b1 = r1[lane], b2 = r2[lane], b3 = r3[lane];
            float b4 = r4[lane], b5 = r5[lane], b6 = r6[lane], b7 = r7[lane];
            a0 += __int_as_float(e0.y) * b0; a1 += __int_as_float(e1.y) * b1;
            a2 += __int_as_float(e2.y) * b2; a3 += __int_as_float(e3.y) * b3;
            a0 += __int_as_float(e4.y) * b4; a1 += __int_as_float(e5.y) * b5;
            a2 += __int_as_float(e6.y) * b6; a3 += __int_as_float(e7.y) * b7;
        }
        // tail: ONE masked 8-wide iteration (over-read hits next segment's valid
        // offsets or the zero pad — values masked to 0)
        if (j < je) {
            int2 e0 = ps[j+0], e1 = ps[j+1], e2 = ps[j+2], e3 = ps[j+3];
            int2 e4 = ps[j+4], e5 = ps[j+5], e6 = ps[j+6], e7 = ps[j+7];
            const float* r0 = (const float*)(bbyte + __builtin_amdgcn_readfirstlane(e0.x));
            const float* r1 = (const float*)(bbyte + __builtin_amdgcn_readfirstlane(e1.x));
            const float* r2 = (const float*)(bbyte + __builtin_amdgcn_readfirstlane(e2.x));
            const float* r3 = (const float*)(bbyte + __builtin_amdgcn_readfirstlane(e3.x));
            const float* r4 = (const float*)(bbyte + __builtin_amdgcn_readfirstlane(e4.x));
            const float* r5 = (const float*)(bbyte + __builtin_amdgcn_readfirstlane(e5.x));
            const float* r6 = (const float*)(bbyte + __builtin_amdgcn_readfirstlane(e6.x));
            const float* r7 = (const float*)(bbyte + __builtin_amdgcn_readfirstlane(e7.x));
            float b0 = r0[lane], b1 = r1[lane], b2 = r2[lane], b3 = r3[lane];
            float b4 = r4[lane], b5 = r5[lane], b6 = r6[lane], b7 = r7[lane];
            float v0 = (j+0 < je) ? __int_as_float(e0.y) : 0.f;
            float v1 = (j+1 < je) ? __int_as_float(e1.y) : 0.f;
            float v2 = (j+2 < je) ? __int_as_float(e2.y) : 0.f;
            float v3 = (j+3 < je) ? __int_as_float(e3.y) : 0.f;
            float v4 = (j+4 < je) ? __int_as_float(e4.y) : 0.f;
            float v5 = (j+5 < je) ? __int_as_float(e5.y) : 0.f;
            float v6 = (j+6 < je) ? __int_as_float(e6.y) : 0.f;
            float v7 = (j+7 < je) ? __int_as_float(e7.y) : 0.f;
            a0 += v0 * b0; a1 += v1 * b1; a2 += v2 * b2; a3 += v3 * b3;
            a0 += v4 * b4; a1 += v5 * b5; a2 += v6 * b6; a3 += v7 * b7;
        }
        out[obase + ((size_t)s << 6) + lane] = (a0 + a1) + (a2 + a3);
    }
}

extern "C" void kernel_launch(void* const* d_in, const int* in_sizes, int n_in,
                              void* d_out, int out_size, void* d_ws, size_t ws_size,
                              hipStream_t stream) {
    const float* values = (const float*)d_in[0];
    const float* b      = (const float*)d_in[1];
    const int*   idx_bh = (const int*)d_in[2];
    const int*   idx_m  = (const int*)d_in[3];
    const int*   idx_k  = (const int*)d_in[4];
    float*       out    = (float*)d_out;
    const int    nnz    = in_sizes[0];

    // ws layout (bytes):
    //   [cursor: 512*CSTR ints @0 (32KB)][ovfcnt @32KB][ovf buf @40KB..512KB]
    //   [packed @512KB: 512 regions x 8192 entries x 8B = 32MB]
    const size_t packed_off = 512 * 1024;
    const size_t need = packed_off + (size_t)NBUCK * CAP2 * sizeof(Pair);

    int*  cursor = (int*)d_ws;                             // padded: one int per 64B
    int*  ovfcnt = (int*)((char*)d_ws + OVFCNT_OFF);
    Pair* ovfbuf = (Pair*)((char*)d_ws + OVFBUF_OFF);
    Pair* packed = (Pair*)((char*)d_ws + packed_off);

    const int nblk = (nnz + TILE - 1) / TILE;   // 512

    if (ws_size >= need) {
        hipMemsetAsync(d_ws, 0, OVFBUF_OFF, stream);       // cursors + ovf cursor
        partition512<<<nblk, PART_T, 0, stream>>>(values, idx_bh, idx_m, idx_k,
                                                  cursor, ovfcnt, ovfbuf, packed, nnz);
        sort_accum<<<NBUCK, 1024, 0, stream>>>(packed, cursor, ovfcnt, ovfbuf, b, out);
    } else {
        hipMemsetAsync(d_out, 0, (size_t)out_size * sizeof(float), stream);
        long long total = (long long)nnz * N_COLS;
        spmm_coo_atomic<<<(unsigned)((total + 255) / 256), 256, 0, stream>>>(
            values, b, idx_bh, idx_m, idx_k, out, nnz);
    }
}